// Round 8
// baseline (592.109 us; speedup 1.0000x reference)
//
#include <hip/hip_runtime.h>

namespace {

constexpr int kB = 8, kCin = 2, kBins = 1024, kFrames = 512;
constexpr int kC = 8, kE = 1024, kN = kB * kFrames; // 4096
constexpr int kNPart = 2048;

typedef _Float16 f16x8 __attribute__((ext_vector_type(8)));
typedef float f32x4 __attribute__((ext_vector_type(4)));

union HPack4 { _Float16 h[4]; uint2 u; };
union HPack2 { _Float16 h[2]; unsigned int u; };

// split v = h + (l/4096), h/l normal-range f16 (denormal-proof)
__device__ inline void splitf(float v, _Float16& h, _Float16& l) {
    float a = (fabsf(v) >= 6.103515625e-05f) ? v : 0.f;
    _Float16 hh = (_Float16)a;
    h = hh;
    l = (_Float16)((v - (float)hh) * 4096.0f);
}

// ================= conv v3: register-resident h1, 2-barrier =================
// grid (32 binchunks, 8 ftiles, 8 b); block 256 = 4 waves.
// wave w: bins [C32 + w*8, +8), lane = frame f (coalesced x reads).
// h1 in registers (full unroll, static indices); FP summation order
// replicates conv_fused_v2 exactly -> v bit-identical -> argmin unchanged.
// Output retile via LDS u32 tile [8c][64f][36] -> 64B-contiguous f16 stores.
__global__ __launch_bounds__(256) void conv_fused_v3(
    const float* __restrict__ x,
    const float* __restrict__ w1, const float* __restrict__ b1,
    const float* __restrict__ w2, const float* __restrict__ b2,
    const float* __restrict__ wsk, const float* __restrict__ bsk,
    _Float16* __restrict__ V1, float* __restrict__ partials)
{
    __shared__ unsigned int vtile[8][64][36];   // {hi16,lo16} packed per value
    __shared__ float w1s[144];
    __shared__ float w2s[64 * 12];
    __shared__ float wsks[16];
    __shared__ float b1s[8], b2s[8], bsks[8];
    __shared__ float reds[256];

    const int t = threadIdx.x;
    const int w = t >> 6, l = t & 63;
    const int C32 = blockIdx.x * 32;
    const int s = C32 + w * 8;           // wave's first output bin
    const int f0 = blockIdx.y * 64;
    const int bb = blockIdx.z;

    if (t < 144) w1s[t] = w1[t];
    for (int i = t; i < 768; i += 256) {
        int cc = i / 12, k = i % 12;
        w2s[cc * 12 + k] = (k < 9) ? w2[cc * 9 + k] : 0.f;
    }
    if (t < 16) wsks[t] = wsk[t];
    if (t < 8) { b1s[t] = b1[t]; b2s[t] = b2[t]; bsks[t] = bsk[t]; }
    __syncthreads();

    // ---- phase 1: x window (bins [s-8, s+16)) + h1[8][16] in registers ----
    float xw[2][24];
    #pragma unroll
    for (int ci = 0; ci < 2; ci++)
        #pragma unroll
        for (int jx = 0; jx < 24; jx++) {
            int gb = s - 8 + jx;
            xw[ci][jx] = (gb >= 0 && gb < kBins)
                ? x[((size_t)(bb * kCin + ci) * kBins + gb) * kFrames + f0 + l]
                : 0.f;
        }

    float h1[8][16];   // h1 bins [s-4, s+12)
    #pragma unroll
    for (int cm = 0; cm < 8; cm++) {
        float wp[18];
        #pragma unroll
        for (int i = 0; i < 18; i++) wp[i] = w1s[cm * 18 + i];
        #pragma unroll
        for (int j = 0; j < 16; j++) {
            int gbh = s - 4 + j;
            float a = b1s[cm];
            #pragma unroll
            for (int ci = 0; ci < 2; ci++)
                #pragma unroll
                for (int k = 0; k < 9; k++)
                    a += xw[ci][j + k] * wp[ci * 9 + k];
            h1[cm][j] = (gbh >= 0 && gbh < kBins) ? (a > 0.f ? a : 0.2f * a) : 0.f;
        }
    }

    // keep only skip-path x values (bins [s, s+8) -> xw index jj+8)
    float xs0[8], xs1[8];
    #pragma unroll
    for (int jj = 0; jj < 8; jj++) { xs0[jj] = xw[0][jj + 8]; xs1[jj] = xw[1][jj + 8]; }

    // ---- phase 2: conv2 + skip per (c, bin); splitf; pack to LDS tile ----
    float sq = 0.f;
    #pragma unroll
    for (int c = 0; c < 8; c++) {
        float acc[8];
        #pragma unroll
        for (int jj = 0; jj < 8; jj++) acc[jj] = b2s[c] + bsks[c];
        #pragma unroll
        for (int ci = 0; ci < 8; ci++) {
            const float4* wp4 = (const float4*)&w2s[(c * 8 + ci) * 12];
            float4 wA = wp4[0], wB = wp4[1], wC = wp4[2];
            float wk[9] = {wA.x, wA.y, wA.z, wA.w, wB.x, wB.y, wB.z, wB.w, wC.x};
            #pragma unroll
            for (int jj = 0; jj < 8; jj++) {
                float sci = 0.f;
                #pragma unroll
                for (int k = 0; k < 9; k++) sci += h1[ci][jj + k] * wk[k];
                acc[jj] += sci;
            }
        }
        unsigned int vals[8];
        #pragma unroll
        for (int jj = 0; jj < 8; jj++) {
            acc[jj] += xs0[jj] * wsks[c * 2] + xs1[jj] * wsks[c * 2 + 1];
            sq += acc[jj] * acc[jj];
            HPack2 p;
            splitf(acc[jj], p.h[0], p.h[1]);
            vals[jj] = p.u;
        }
        *(uint4*)&vtile[c][l][w * 8] =
            make_uint4(vals[0], vals[1], vals[2], vals[3]);
        *(uint4*)&vtile[c][l][w * 8 + 4] =
            make_uint4(vals[4], vals[5], vals[6], vals[7]);
    }
    __syncthreads();

    // ---- phase 3: 64B-contiguous stores of both planes ----
    _Float16* V2 = V1 + (size_t)33554432;
    #pragma unroll
    for (int it = 0; it < 2; it++) {
        const int p = it * 256 + t;
        const int c = p >> 6, f = p & 63;
        const size_t vbase = ((size_t)(c * kN + bb * kFrames + f0 + f)) * kBins + C32;
        #pragma unroll
        for (int g = 0; g < 4; g++) {
            uint4 a = *(const uint4*)&vtile[c][f][g * 8];
            uint4 b = *(const uint4*)&vtile[c][f][g * 8 + 4];
            uint4 h4, l4;
            h4.x = (a.x & 0xffffu) | (a.y << 16);
            h4.y = (a.z & 0xffffu) | (a.w << 16);
            h4.z = (b.x & 0xffffu) | (b.y << 16);
            h4.w = (b.z & 0xffffu) | (b.w << 16);
            l4.x = (a.x >> 16) | (a.y & 0xffff0000u);
            l4.y = (a.z >> 16) | (a.w & 0xffff0000u);
            l4.z = (b.x >> 16) | (b.y & 0xffff0000u);
            l4.w = (b.z >> 16) | (b.w & 0xffff0000u);
            *(uint4*)&V1[vbase + g * 8] = h4;
            *(uint4*)&V2[vbase + g * 8] = l4;
        }
    }

    // ---- per-block sum(v^2) partial ----
    reds[t] = sq;
    __syncthreads();
    for (int off = 128; off > 0; off >>= 1) {
        if (t < off) reds[t] += reds[t + off];
        __syncthreads();
    }
    if (t == 0) {
        int blin = (blockIdx.z * gridDim.y + blockIdx.y) * gridDim.x + blockIdx.x;
        partials[blin] = reds[0];
    }
}

// ================= codebook split + e2 (+ pk init) =================
__global__ __launch_bounds__(256) void cbsplit_e2(
    const float* __restrict__ cb, _Float16* __restrict__ B1,
    float* __restrict__ e2, unsigned long long* __restrict__ pk)
{
    const int gid = blockIdx.x * 256 + threadIdx.x;
    if (gid < kC * kN) pk[gid] = ~0ull;

    const int gw = gid >> 6;
    const int lane = threadIdx.x & 63;
    _Float16* B2 = B1 + (size_t)8388608;
    const float* row = cb + (size_t)gw * kBins;
    float s = 0.f;
    #pragma unroll
    for (int j = 0; j < 4; j++) {
        float4 v = *(const float4*)&row[lane * 4 + j * 256];
        s += v.x * v.x + v.y * v.y + v.z * v.z + v.w * v.w;
        HPack4 ph, pl;
        splitf(v.x, ph.h[0], pl.h[0]);
        splitf(v.y, ph.h[1], pl.h[1]);
        splitf(v.z, ph.h[2], pl.h[2]);
        splitf(v.w, ph.h[3], pl.h[3]);
        size_t off = (size_t)gw * kBins + lane * 4 + j * 256;
        *(uint2*)&B1[off] = ph.u;
        *(uint2*)&B2[off] = pl.u;
    }
    #pragma unroll
    for (int off = 32; off > 0; off >>= 1) s += __shfl_down(s, off);
    if (lane == 0) e2[gw] = s;
}

// ================= MFMA distance + argmin, 2-buffer + 2 blocks/CU ==========
// (round-5 proven kernel, verbatim: 197 us, MfmaUtil ~50%)
__global__ __launch_bounds__(256, 2) void dist_mfma(
    const _Float16* __restrict__ V1, const _Float16* __restrict__ B1p,
    const float* __restrict__ e2, unsigned long long* __restrict__ pk)
{
    __shared__ char smem[2 * 32768 + 2048];

    const int t = threadIdx.x;
    const int bidx = blockIdx.x;
    const int ch = bidx & 7;
    const int eh = (bidx >> 3) & 1;
    const int n0 = (bidx >> 4) * 128;
    const int w = t >> 6, lane = t & 63;
    const int l15 = lane & 15, kc4 = lane >> 4;
    const int wm = w >> 1, we = w & 1;

    float* lds_e2 = (float*)(smem + 65536);
    {
        const float* e2c = e2 + ch * kE + eh * 512;
        float a = e2c[t], b = e2c[t + 256];
        lds_e2[t] = a;
        lds_e2[t + 256] = b;
    }

    // staging source pointers (K-invariant parts)
    const _Float16* srcA[4];
    const _Float16* srcB[4];
    int dstoff[4];
    #pragma unroll
    for (int i = 0; i < 4; i++) {
        int ci = w * 256 + i * 64 + lane;
        int row = ci >> 3, slot = ci & 7;
        int g = slot ^ (row & 7);
        int p = g >> 2, kc = g & 3;
        srcA[i] = V1 + (size_t)p * 33554432 + ((size_t)(ch * kN + n0 + row)) * kBins + kc * 8;
        srcB[i] = B1p + (size_t)p * 8388608 + ((size_t)(ch * kE + row)) * kBins + kc * 8;
        dstoff[i] = (w * 256 + i * 64) * 16;
    }

    // fragment read bases (XOR-swizzled slots; conflict-free)
    const int rowA = wm * 64 + l15;
    const int rowB = we * 64 + l15;
    const int baseA1 = rowA * 128 + ((kc4) ^ (rowA & 7)) * 16;
    const int baseA2 = rowA * 128 + ((4 + kc4) ^ (rowA & 7)) * 16;
    const int baseB1 = 16384 + rowB * 128 + ((kc4) ^ (rowB & 7)) * 16;
    const int baseB2 = 16384 + rowB * 128 + ((4 + kc4) ^ (rowB & 7)) * 16;

    float rm[16];
    int ri[16];
    #pragma unroll
    for (int s = 0; s < 16; s++) { rm[s] = 3.4e38f; ri[s] = 0; }

    typedef const __attribute__((address_space(1))) void gsrc_t;
    typedef __attribute__((address_space(3))) void gdst_t;

    auto issue = [&](int jj) {
        const int k0 = (jj & 31) * 32;
        const size_t etoff = (size_t)(eh * 4 + (jj >> 5)) * 128 * kBins + k0;
        char* nb = smem + (jj & 1) * 32768;
        #pragma unroll
        for (int i = 0; i < 4; i++)
            __builtin_amdgcn_global_load_lds((gsrc_t*)(srcA[i] + k0), (gdst_t*)(nb + dstoff[i]), 16, 0, 0);
        #pragma unroll
        for (int i = 0; i < 4; i++)
            __builtin_amdgcn_global_load_lds((gsrc_t*)(srcB[i] + etoff), (gdst_t*)(nb + 16384 + dstoff[i]), 16, 0, 0);
    };

    f32x4 hi[4][4], lo[4][4];
    #pragma unroll
    for (int mi = 0; mi < 4; mi++)
        #pragma unroll
        for (int ei = 0; ei < 4; ei++) {
            hi[mi][ei] = (f32x4){0.f, 0.f, 0.f, 0.f};
            lo[mi][ei] = (f32x4){0.f, 0.f, 0.f, 0.f};
        }

    __syncthreads();            // e2 staged (its loads drained); LDS clean

    issue(0);

    #pragma unroll 1
    for (int et = 0; et < 4; et++) {
        #pragma unroll 1
        for (int ks = 0; ks < 32; ks++) {
            const int j = et * 32 + ks;
            asm volatile("s_waitcnt vmcnt(0)\n\ts_barrier" ::: "memory");
            if (j < 127) issue(j + 1);

            const char* buf = smem + (j & 1) * 32768;
            f16x8 a1[4], a2[4], b1f[4], b2f[4];
            #pragma unroll
            for (int mi = 0; mi < 4; mi++) {
                a1[mi] = *(const f16x8*)(buf + baseA1 + mi * 2048);
                a2[mi] = *(const f16x8*)(buf + baseA2 + mi * 2048);
            }
            #pragma unroll
            for (int ei = 0; ei < 4; ei++) {
                b1f[ei] = *(const f16x8*)(buf + baseB1 + ei * 2048);
                b2f[ei] = *(const f16x8*)(buf + baseB2 + ei * 2048);
            }
            __builtin_amdgcn_s_setprio(1);
            #pragma unroll
            for (int mi = 0; mi < 4; mi++)
                #pragma unroll
                for (int ei = 0; ei < 4; ei++) {
                    hi[mi][ei] = __builtin_amdgcn_mfma_f32_16x16x32_f16(a1[mi], b1f[ei], hi[mi][ei], 0, 0, 0);
                    lo[mi][ei] = __builtin_amdgcn_mfma_f32_16x16x32_f16(a1[mi], b2f[ei], lo[mi][ei], 0, 0, 0);
                    lo[mi][ei] = __builtin_amdgcn_mfma_f32_16x16x32_f16(a2[mi], b1f[ei], lo[mi][ei], 0, 0, 0);
                }
            __builtin_amdgcn_s_setprio(0);
        }

        // epilogue: running argmin (ascending e, strict <); e2 from LDS
        #pragma unroll
        for (int ei = 0; ei < 4; ei++) {
            const int eloc = et * 128 + we * 64 + ei * 16 + l15;
            const float ev = lds_e2[eloc];
            const int eix = eh * 512 + eloc;
            #pragma unroll
            for (int mi = 0; mi < 4; mi++) {
                f32x4 dot4 = hi[mi][ei] + lo[mi][ei] * (1.0f / 4096.0f);
                #pragma unroll
                for (int rr = 0; rr < 4; rr++) {
                    float d = ev - 2.0f * dot4[rr];
                    int s = mi * 4 + rr;
                    if (d < rm[s]) { rm[s] = d; ri[s] = eix; }
                }
                hi[mi][ei] = (f32x4){0.f, 0.f, 0.f, 0.f};
                lo[mi][ei] = (f32x4){0.f, 0.f, 0.f, 0.f};
            }
        }
    }

    // cross-lane reduce over the 16 lanes sharing the same rows
    #pragma unroll
    for (int m = 1; m < 16; m <<= 1) {
        #pragma unroll
        for (int s = 0; s < 16; s++) {
            float ov = __shfl_xor(rm[s], m);
            int oi = __shfl_xor(ri[s], m);
            if (ov < rm[s] || (ov == rm[s] && oi < ri[s])) { rm[s] = ov; ri[s] = oi; }
        }
    }

    // merge the 2 waves sharing each row range
    float* mv = (float*)smem;           // [128][2]
    int* miv = (int*)(smem + 1024);     // [128][2]
    __syncthreads();
    if (l15 == 0) {
        #pragma unroll
        for (int s = 0; s < 16; s++) {
            int mi = s >> 2, rr = s & 3;
            int rloc = wm * 64 + mi * 16 + (lane >> 4) * 4 + rr;
            mv[rloc * 2 + we] = rm[s];
            miv[rloc * 2 + we] = ri[s];
        }
    }
    __syncthreads();
    if (t < 128) {
        float v0 = mv[t * 2], v1 = mv[t * 2 + 1];
        int i0 = miv[t * 2], i1 = miv[t * 2 + 1];
        bool take1 = (v1 < v0) || (v1 == v0 && i1 < i0);
        float bv = take1 ? v1 : v0;
        int bi = take1 ? i1 : i0;
        unsigned int u = __float_as_uint(bv);
        unsigned int su = (u & 0x80000000u) ? ~u : (u ^ 0x80000000u);
        unsigned long long packed = ((unsigned long long)su << 32) | (unsigned int)bi;
        atomicMin(&pk[ch * kN + n0 + t], packed);
    }
}

// ================= gather (cp-XCD affine) + fused loss =====================
__global__ __launch_bounds__(256) void gather_pk(
    const float* __restrict__ cb, const unsigned long long* __restrict__ pk,
    const float* __restrict__ partials, float* __restrict__ out,
    float* __restrict__ loss)
{
    const int t = threadIdx.x;
    const int lane = t & 63, q = t >> 6;
    const int b = blockIdx.x;
    const int cp = b & 7;            // channel -> XCD affinity (cb panel L2-fits)
    const int bt = (b >> 3) & 63;    // 64 bin-tiles of 16
    const int ftile = (b >> 9) & 7;  // 8 frame tiles of 64
    const int bb = b >> 12;          // batch
    const int co = (kC - 1) - cp;
    const int f = ftile * 64 + lane;
    const int n = bb * kFrames + f;
    const int e = (int)(unsigned int)(pk[cp * kN + n] & 0xFFFFFFFFull);
    const int bin0 = bt * 16 + q * 4;
    const float4 v4 = *(const float4*)&cb[((size_t)cp * kE + e) * kBins + bin0];
    const size_t base = ((size_t)(bb * kC + co) * kBins + bin0) * kFrames + f;
    out[base] = v4.x;
    out[base + kFrames] = v4.y;
    out[base + 2 * (size_t)kFrames] = v4.z;
    out[base + 3 * (size_t)kFrames] = v4.w;

    if (b == 32767) {
        __shared__ float reds[256];
        float s = 0.f;
        for (int i = t; i < kC * kN; i += 256) {
            unsigned int su = (unsigned int)(pk[i] >> 32);
            unsigned int u = (su & 0x80000000u) ? (su ^ 0x80000000u) : ~su;
            s += __uint_as_float(u);
        }
        for (int i = t; i < kNPart; i += 256) s += partials[i];
        reds[t] = s;
        __syncthreads();
        for (int off = 128; off > 0; off >>= 1) {
            if (t < off) reds[t] += reds[t + off];
            __syncthreads();
        }
        if (t == 0) loss[0] = 1.25f * reds[0] / (float)(kN * kBins);
    }
}

} // namespace

extern "C" void kernel_launch(void* const* d_in, const int* in_sizes, int n_in,
                              void* d_out, int out_size, void* d_ws, size_t ws_size,
                              hipStream_t stream)
{
    const float* x   = (const float*)d_in[0];
    const float* w1  = (const float*)d_in[1];
    const float* b1  = (const float*)d_in[2];
    const float* w2  = (const float*)d_in[3];
    const float* b2  = (const float*)d_in[4];
    const float* wsk = (const float*)d_in[5];
    const float* bsk = (const float*)d_in[6];
    const float* cb  = (const float*)d_in[7];
    float* out = (float*)d_out;
    char* ws = (char*)d_ws;

    // ws layout: B1|B2 32M | e2 32K | pk 256K | partials 8K
    _Float16* B1 = (_Float16*)ws;
    float* e2                  = (float*)(ws + 33554432);
    unsigned long long* pk     = (unsigned long long*)(ws + 33554432 + 32768);
    float* partials            = (float*)(ws + 33554432 + 32768 + 262144);
    _Float16* V1 = (_Float16*)d_out; // V1 67MB | V2 67MB, overwritten by gather

    conv_fused_v3<<<dim3(32, 8, 8), 256, 0, stream>>>(
        x, w1, b1, w2, b2, wsk, bsk, V1, partials);
    cbsplit_e2<<<(kC * kE) / 4, 256, 0, stream>>>(cb, B1, e2, pk);
    dist_mfma<<<dim3(512), 256, 0, stream>>>(V1, B1, e2, pk);
    gather_pk<<<dim3(32768), 256, 0, stream>>>(cb, pk, partials, out,
                                               out + (size_t)kC * kBins * kN);
}

// Round 9
// 425.824 us; speedup vs baseline: 1.3905x; 1.3905x over previous
//
#include <hip/hip_runtime.h>

namespace {

constexpr int kB = 8, kCin = 2, kBins = 1024, kFrames = 512;
constexpr int kC = 8, kE = 1024, kN = kB * kFrames; // 4096
constexpr int kNPart = 4096;

typedef _Float16 f16x8 __attribute__((ext_vector_type(8)));
typedef float f32x4 __attribute__((ext_vector_type(4)));

union HPack4 { _Float16 h[4]; uint2 u; };
union HPack8 { _Float16 h[8]; uint4 u; };

// split v = h + (l/4096), h/l normal-range f16 (denormal-proof)
__device__ inline void splitf(float v, _Float16& h, _Float16& l) {
    float a = (fabsf(v) >= 6.103515625e-05f) ? v : 0.f;
    _Float16 hh = (_Float16)a;
    h = hh;
    l = (_Float16)((v - (float)hh) * 4096.0f);
}

// ================= conv v4: v2 skeleton, thread=(fi,c) main stage ==========
// grid (32 binchunks, 16 ftiles, 8 b) = 4096 blocks; block 256 = 4 waves.
// Stage x + h1 in LDS exactly as v2 (bit-identical h1t). Main stage: thread
// (fi = t&31, c = t>>5) computes one channel x 32 bins; w2 reads are
// wave-broadcast; outputs packed in-register and stored as 64B-contiguous
// f16 runs (no vbuf retile, 3 barriers total). Summation order identical
// to v2 (ci ascending, k ascending, skip last) -> v bit-exact.
constexpr int BT = 32, FT = 32, XB = BT + 16, HB = BT + 8;

__global__ __launch_bounds__(256) void conv_fused_v4(
    const float* __restrict__ x,
    const float* __restrict__ w1, const float* __restrict__ b1,
    const float* __restrict__ w2, const float* __restrict__ b2,
    const float* __restrict__ wsk, const float* __restrict__ bsk,
    _Float16* __restrict__ V1, float* __restrict__ partials)
{
    __shared__ float xt[kCin][XB][33];
    __shared__ float h1t[kC][HB][33];
    __shared__ float w1s[144];
    __shared__ float w2s[kC * kC][12];
    __shared__ float wsks[16];
    __shared__ float b1s[8], b2s[8], bsks[8];
    __shared__ float reds[256];

    const int t = threadIdx.x;
    const int bt = blockIdx.x, ft = blockIdx.y, bb = blockIdx.z;
    const int bs = bt * BT, f0 = ft * FT;
    _Float16* V2 = V1 + (size_t)33554432;

    if (t < 144) w1s[t] = w1[t];
    for (int i = t; i < 768; i += 256) {
        int cc = i / 12, k = i % 12;
        w2s[cc][k] = (k < 9) ? w2[cc * 9 + k] : 0.f;
    }
    if (t < 16) wsks[t] = wsk[t];
    if (t < 8) { b1s[t] = b1[t]; b2s[t] = b2[t]; bsks[t] = bsk[t]; }

    // stage x tile [bs-8, bs+40)  (verbatim v2)
    for (int i = t; i < kCin * XB * FT; i += 256) {
        int fi = i % FT, xb = (i / FT) % XB, ci = i / (FT * XB);
        int gb = bs - 8 + xb;
        float v = 0.f;
        if (gb >= 0 && gb < kBins)
            v = x[((bb * kCin + ci) * kBins + gb) * kFrames + f0 + fi];
        xt[ci][xb][fi] = v;
    }
    __syncthreads();

    const int fi = t & 31;
    const int r = t >> 5; // 0..7

    // h1 stage (verbatim v2): thread (fi, r) -> h1t[r][0..39][fi]
    for (int q = 0; q < 5; q++) {
        float a8[8];
        #pragma unroll
        for (int jj = 0; jj < 8; jj++) a8[jj] = b1s[r];
        #pragma unroll
        for (int ci = 0; ci < kCin; ci++) {
            float w[16];
            #pragma unroll
            for (int k = 0; k < 16; k++) w[k] = xt[ci][q * 8 + k][fi];
            const float* wp = &w1s[(r * kCin + ci) * 9];
            #pragma unroll
            for (int jj = 0; jj < 8; jj++)
                #pragma unroll
                for (int k = 0; k < 9; k++)
                    a8[jj] += w[jj + k] * wp[k];
        }
        #pragma unroll
        for (int jj = 0; jj < 8; jj++) {
            int hb = q * 8 + jj;
            int gb = bs - 4 + hb;
            float v = (gb >= 0 && gb < kBins) ? (a8[jj] > 0.f ? a8[jj] : 0.2f * a8[jj]) : 0.f;
            h1t[r][hb][fi] = v;
        }
    }
    __syncthreads();

    // main stage: thread (fi, c=r) computes channel r for 32 bins
    const int c = r;
    float acc[32];
    #pragma unroll
    for (int j = 0; j < 32; j++) acc[j] = b2s[c] + bsks[c];

    #pragma unroll 1
    for (int ci = 0; ci < 8; ci++) {
        const float4* wp4 = (const float4*)&w2s[c * 8 + ci][0];
        float4 wA = wp4[0], wB = wp4[1], wC = wp4[2];
        float wk[9] = {wA.x, wA.y, wA.z, wA.w, wB.x, wB.y, wB.z, wB.w, wC.x};
        float w[40];
        #pragma unroll
        for (int k = 0; k < 40; k++) w[k] = h1t[ci][k][fi];
        #pragma unroll
        for (int j = 0; j < 32; j++) {
            float s = 0.f;
            #pragma unroll
            for (int k = 0; k < 9; k++) s += w[j + k] * wk[k];
            acc[j] += s;
        }
    }

    // skip path + sum(v^2)
    float sq = 0.f;
    #pragma unroll
    for (int j = 0; j < 32; j++) {
        float x0 = xt[0][j + 8][fi];
        float x1 = xt[1][j + 8][fi];
        acc[j] += x0 * wsks[c * 2] + x1 * wsks[c * 2 + 1];
        sq += acc[j] * acc[j];
    }

    // pack + store: 4 groups of 8 consecutive bins -> 16B per plane per group
    const int n = bb * kFrames + f0 + fi;
    const size_t vbase = ((size_t)(c * kN + n)) * kBins + bs;
    #pragma unroll
    for (int g = 0; g < 4; g++) {
        HPack8 ph, pl;
        #pragma unroll
        for (int j = 0; j < 8; j++)
            splitf(acc[g * 8 + j], ph.h[j], pl.h[j]);
        *(uint4*)&V1[vbase + g * 8] = ph.u;
        *(uint4*)&V2[vbase + g * 8] = pl.u;
    }

    // per-block sum(v^2) partial
    reds[t] = sq;
    __syncthreads();
    for (int off = 128; off > 0; off >>= 1) {
        if (t < off) reds[t] += reds[t + off];
        __syncthreads();
    }
    if (t == 0) {
        int blin = (bb * gridDim.y + blockIdx.y) * gridDim.x + blockIdx.x;
        partials[blin] = reds[0];
    }
}

// ================= codebook split + e2 (+ pk init) =================
__global__ __launch_bounds__(256) void cbsplit_e2(
    const float* __restrict__ cb, _Float16* __restrict__ B1,
    float* __restrict__ e2, unsigned long long* __restrict__ pk)
{
    const int gid = blockIdx.x * 256 + threadIdx.x;
    if (gid < kC * kN) pk[gid] = ~0ull;

    const int gw = gid >> 6;
    const int lane = threadIdx.x & 63;
    _Float16* B2 = B1 + (size_t)8388608;
    const float* row = cb + (size_t)gw * kBins;
    float s = 0.f;
    #pragma unroll
    for (int j = 0; j < 4; j++) {
        float4 v = *(const float4*)&row[lane * 4 + j * 256];
        s += v.x * v.x + v.y * v.y + v.z * v.z + v.w * v.w;
        HPack4 ph, pl;
        splitf(v.x, ph.h[0], pl.h[0]);
        splitf(v.y, ph.h[1], pl.h[1]);
        splitf(v.z, ph.h[2], pl.h[2]);
        splitf(v.w, ph.h[3], pl.h[3]);
        size_t off = (size_t)gw * kBins + lane * 4 + j * 256;
        *(uint2*)&B1[off] = ph.u;
        *(uint2*)&B2[off] = pl.u;
    }
    #pragma unroll
    for (int off = 32; off > 0; off >>= 1) s += __shfl_down(s, off);
    if (lane == 0) e2[gw] = s;
}

// ================= MFMA distance + argmin, 2-buffer + 2 blocks/CU ==========
// (round-5 proven kernel, verbatim: 197 us, MfmaUtil ~50%)
__global__ __launch_bounds__(256, 2) void dist_mfma(
    const _Float16* __restrict__ V1, const _Float16* __restrict__ B1p,
    const float* __restrict__ e2, unsigned long long* __restrict__ pk)
{
    __shared__ char smem[2 * 32768 + 2048];

    const int t = threadIdx.x;
    const int bidx = blockIdx.x;
    const int ch = bidx & 7;
    const int eh = (bidx >> 3) & 1;
    const int n0 = (bidx >> 4) * 128;
    const int w = t >> 6, lane = t & 63;
    const int l15 = lane & 15, kc4 = lane >> 4;
    const int wm = w >> 1, we = w & 1;

    float* lds_e2 = (float*)(smem + 65536);
    {
        const float* e2c = e2 + ch * kE + eh * 512;
        float a = e2c[t], b = e2c[t + 256];
        lds_e2[t] = a;
        lds_e2[t + 256] = b;
    }

    // staging source pointers (K-invariant parts)
    const _Float16* srcA[4];
    const _Float16* srcB[4];
    int dstoff[4];
    #pragma unroll
    for (int i = 0; i < 4; i++) {
        int ci = w * 256 + i * 64 + lane;
        int row = ci >> 3, slot = ci & 7;
        int g = slot ^ (row & 7);
        int p = g >> 2, kc = g & 3;
        srcA[i] = V1 + (size_t)p * 33554432 + ((size_t)(ch * kN + n0 + row)) * kBins + kc * 8;
        srcB[i] = B1p + (size_t)p * 8388608 + ((size_t)(ch * kE + row)) * kBins + kc * 8;
        dstoff[i] = (w * 256 + i * 64) * 16;
    }

    // fragment read bases (XOR-swizzled slots; conflict-free)
    const int rowA = wm * 64 + l15;
    const int rowB = we * 64 + l15;
    const int baseA1 = rowA * 128 + ((kc4) ^ (rowA & 7)) * 16;
    const int baseA2 = rowA * 128 + ((4 + kc4) ^ (rowA & 7)) * 16;
    const int baseB1 = 16384 + rowB * 128 + ((kc4) ^ (rowB & 7)) * 16;
    const int baseB2 = 16384 + rowB * 128 + ((4 + kc4) ^ (rowB & 7)) * 16;

    float rm[16];
    int ri[16];
    #pragma unroll
    for (int s = 0; s < 16; s++) { rm[s] = 3.4e38f; ri[s] = 0; }

    typedef const __attribute__((address_space(1))) void gsrc_t;
    typedef __attribute__((address_space(3))) void gdst_t;

    auto issue = [&](int jj) {
        const int k0 = (jj & 31) * 32;
        const size_t etoff = (size_t)(eh * 4 + (jj >> 5)) * 128 * kBins + k0;
        char* nb = smem + (jj & 1) * 32768;
        #pragma unroll
        for (int i = 0; i < 4; i++)
            __builtin_amdgcn_global_load_lds((gsrc_t*)(srcA[i] + k0), (gdst_t*)(nb + dstoff[i]), 16, 0, 0);
        #pragma unroll
        for (int i = 0; i < 4; i++)
            __builtin_amdgcn_global_load_lds((gsrc_t*)(srcB[i] + etoff), (gdst_t*)(nb + 16384 + dstoff[i]), 16, 0, 0);
    };

    f32x4 hi[4][4], lo[4][4];
    #pragma unroll
    for (int mi = 0; mi < 4; mi++)
        #pragma unroll
        for (int ei = 0; ei < 4; ei++) {
            hi[mi][ei] = (f32x4){0.f, 0.f, 0.f, 0.f};
            lo[mi][ei] = (f32x4){0.f, 0.f, 0.f, 0.f};
        }

    __syncthreads();            // e2 staged (its loads drained); LDS clean

    issue(0);

    #pragma unroll 1
    for (int et = 0; et < 4; et++) {
        #pragma unroll 1
        for (int ks = 0; ks < 32; ks++) {
            const int j = et * 32 + ks;
            asm volatile("s_waitcnt vmcnt(0)\n\ts_barrier" ::: "memory");
            if (j < 127) issue(j + 1);

            const char* buf = smem + (j & 1) * 32768;
            f16x8 a1[4], a2[4], b1f[4], b2f[4];
            #pragma unroll
            for (int mi = 0; mi < 4; mi++) {
                a1[mi] = *(const f16x8*)(buf + baseA1 + mi * 2048);
                a2[mi] = *(const f16x8*)(buf + baseA2 + mi * 2048);
            }
            #pragma unroll
            for (int ei = 0; ei < 4; ei++) {
                b1f[ei] = *(const f16x8*)(buf + baseB1 + ei * 2048);
                b2f[ei] = *(const f16x8*)(buf + baseB2 + ei * 2048);
            }
            __builtin_amdgcn_s_setprio(1);
            #pragma unroll
            for (int mi = 0; mi < 4; mi++)
                #pragma unroll
                for (int ei = 0; ei < 4; ei++) {
                    hi[mi][ei] = __builtin_amdgcn_mfma_f32_16x16x32_f16(a1[mi], b1f[ei], hi[mi][ei], 0, 0, 0);
                    lo[mi][ei] = __builtin_amdgcn_mfma_f32_16x16x32_f16(a1[mi], b2f[ei], lo[mi][ei], 0, 0, 0);
                    lo[mi][ei] = __builtin_amdgcn_mfma_f32_16x16x32_f16(a2[mi], b1f[ei], lo[mi][ei], 0, 0, 0);
                }
            __builtin_amdgcn_s_setprio(0);
        }

        // epilogue: running argmin (ascending e, strict <); e2 from LDS
        #pragma unroll
        for (int ei = 0; ei < 4; ei++) {
            const int eloc = et * 128 + we * 64 + ei * 16 + l15;
            const float ev = lds_e2[eloc];
            const int eix = eh * 512 + eloc;
            #pragma unroll
            for (int mi = 0; mi < 4; mi++) {
                f32x4 dot4 = hi[mi][ei] + lo[mi][ei] * (1.0f / 4096.0f);
                #pragma unroll
                for (int rr = 0; rr < 4; rr++) {
                    float d = ev - 2.0f * dot4[rr];
                    int s = mi * 4 + rr;
                    if (d < rm[s]) { rm[s] = d; ri[s] = eix; }
                }
                hi[mi][ei] = (f32x4){0.f, 0.f, 0.f, 0.f};
                lo[mi][ei] = (f32x4){0.f, 0.f, 0.f, 0.f};
            }
        }
    }

    // cross-lane reduce over the 16 lanes sharing the same rows
    #pragma unroll
    for (int m = 1; m < 16; m <<= 1) {
        #pragma unroll
        for (int s = 0; s < 16; s++) {
            float ov = __shfl_xor(rm[s], m);
            int oi = __shfl_xor(ri[s], m);
            if (ov < rm[s] || (ov == rm[s] && oi < ri[s])) { rm[s] = ov; ri[s] = oi; }
        }
    }

    // merge the 2 waves sharing each row range
    float* mv = (float*)smem;           // [128][2]
    int* miv = (int*)(smem + 1024);     // [128][2]
    __syncthreads();
    if (l15 == 0) {
        #pragma unroll
        for (int s = 0; s < 16; s++) {
            int mi = s >> 2, rr = s & 3;
            int rloc = wm * 64 + mi * 16 + (lane >> 4) * 4 + rr;
            mv[rloc * 2 + we] = rm[s];
            miv[rloc * 2 + we] = ri[s];
        }
    }
    __syncthreads();
    if (t < 128) {
        float v0 = mv[t * 2], v1 = mv[t * 2 + 1];
        int i0 = miv[t * 2], i1 = miv[t * 2 + 1];
        bool take1 = (v1 < v0) || (v1 == v0 && i1 < i0);
        float bv = take1 ? v1 : v0;
        int bi = take1 ? i1 : i0;
        unsigned int u = __float_as_uint(bv);
        unsigned int su = (u & 0x80000000u) ? ~u : (u ^ 0x80000000u);
        unsigned long long packed = ((unsigned long long)su << 32) | (unsigned int)bi;
        atomicMin(&pk[ch * kN + n0 + t], packed);
    }
}

// ================= gather (cp-XCD affine) + fused loss =====================
__global__ __launch_bounds__(256) void gather_pk(
    const float* __restrict__ cb, const unsigned long long* __restrict__ pk,
    const float* __restrict__ partials, float* __restrict__ out,
    float* __restrict__ loss)
{
    const int t = threadIdx.x;
    const int lane = t & 63, q = t >> 6;
    const int b = blockIdx.x;
    const int cp = b & 7;            // channel -> XCD affinity (cb panel L2-fits)
    const int bt = (b >> 3) & 63;    // 64 bin-tiles of 16
    const int ftile = (b >> 9) & 7;  // 8 frame tiles of 64
    const int bb = b >> 12;          // batch
    const int co = (kC - 1) - cp;
    const int f = ftile * 64 + lane;
    const int n = bb * kFrames + f;
    const int e = (int)(unsigned int)(pk[cp * kN + n] & 0xFFFFFFFFull);
    const int bin0 = bt * 16 + q * 4;
    const float4 v4 = *(const float4*)&cb[((size_t)cp * kE + e) * kBins + bin0];
    const size_t base = ((size_t)(bb * kC + co) * kBins + bin0) * kFrames + f;
    out[base] = v4.x;
    out[base + kFrames] = v4.y;
    out[base + 2 * (size_t)kFrames] = v4.z;
    out[base + 3 * (size_t)kFrames] = v4.w;

    if (b == 32767) {
        __shared__ float reds[256];
        float s = 0.f;
        for (int i = t; i < kC * kN; i += 256) {
            unsigned int su = (unsigned int)(pk[i] >> 32);
            unsigned int u = (su & 0x80000000u) ? (su ^ 0x80000000u) : ~su;
            s += __uint_as_float(u);
        }
        for (int i = t; i < kNPart; i += 256) s += partials[i];
        reds[t] = s;
        __syncthreads();
        for (int off = 128; off > 0; off >>= 1) {
            if (t < off) reds[t] += reds[t + off];
            __syncthreads();
        }
        if (t == 0) loss[0] = 1.25f * reds[0] / (float)(kN * kBins);
    }
}

} // namespace

extern "C" void kernel_launch(void* const* d_in, const int* in_sizes, int n_in,
                              void* d_out, int out_size, void* d_ws, size_t ws_size,
                              hipStream_t stream)
{
    const float* x   = (const float*)d_in[0];
    const float* w1  = (const float*)d_in[1];
    const float* b1  = (const float*)d_in[2];
    const float* w2  = (const float*)d_in[3];
    const float* b2  = (const float*)d_in[4];
    const float* wsk = (const float*)d_in[5];
    const float* bsk = (const float*)d_in[6];
    const float* cb  = (const float*)d_in[7];
    float* out = (float*)d_out;
    char* ws = (char*)d_ws;

    // ws layout: B1|B2 32M | e2 32K | pk 256K | partials 16K
    _Float16* B1 = (_Float16*)ws;
    float* e2                  = (float*)(ws + 33554432);
    unsigned long long* pk     = (unsigned long long*)(ws + 33554432 + 32768);
    float* partials            = (float*)(ws + 33554432 + 32768 + 262144);
    _Float16* V1 = (_Float16*)d_out; // V1 67MB | V2 67MB, overwritten by gather

    conv_fused_v4<<<dim3(32, 16, 8), 256, 0, stream>>>(
        x, w1, b1, w2, b2, wsk, bsk, V1, partials);
    cbsplit_e2<<<(kC * kE) / 4, 256, 0, stream>>>(cb, B1, e2, pk);
    dist_mfma<<<dim3(512), 256, 0, stream>>>(V1, B1, e2, pk);
    gather_pk<<<dim3(32768), 256, 0, stream>>>(cb, pk, partials, out,
                                               out + (size_t)kC * kBins * kN);
}

// Round 10
// 409.823 us; speedup vs baseline: 1.4448x; 1.0390x over previous
//
#include <hip/hip_runtime.h>

namespace {

constexpr int kB = 8, kCin = 2, kBins = 1024, kFrames = 512;
constexpr int kC = 8, kE = 1024, kN = kB * kFrames; // 4096

typedef _Float16 f16x8 __attribute__((ext_vector_type(8)));
typedef float f32x4 __attribute__((ext_vector_type(4)));

union HPack4 { _Float16 h[4]; uint2 u; };

// split v = h + (l/4096), h/l normal-range f16 (denormal-proof)
__device__ inline void splitf(float v, _Float16& h, _Float16& l) {
    float a = (fabsf(v) >= 6.103515625e-05f) ? v : 0.f;
    _Float16 hh = (_Float16)a;
    h = hh;
    l = (_Float16)((v - (float)hh) * 4096.0f);
}

// ================= conv (fused conv1->lrelu->conv2+skip), r7-proven ========
constexpr int BT = 32, FT = 32, XB = BT + 16, HB = BT + 8;

__global__ __launch_bounds__(256) void conv_fused_v2(
    const float* __restrict__ x,
    const float* __restrict__ w1, const float* __restrict__ b1,
    const float* __restrict__ w2, const float* __restrict__ b2,
    const float* __restrict__ wsk, const float* __restrict__ bsk,
    _Float16* __restrict__ V1, float* __restrict__ partials)
{
    __shared__ float xt[kCin][XB][33];
    __shared__ float h1t[kC][HB][33];
    __shared__ float vbuf[BT][33];
    __shared__ float w1s[kC * kCin * 9];
    __shared__ float w2s[kC * kC][12];
    __shared__ float wsks[kC * kCin];
    __shared__ float b1s[kC], b2s[kC], bsks[kC];
    __shared__ float reds[256];

    const int t = threadIdx.x;
    const int bt = blockIdx.x, ft = blockIdx.y, bb = blockIdx.z;
    const int bs = bt * BT, f0 = ft * FT;
    _Float16* V2 = V1 + (size_t)33554432;

    for (int i = t; i < kC * kCin * 9; i += 256) w1s[i] = w1[i];
    for (int i = t; i < 768; i += 256) {
        int cc = i / 12, k = i % 12;
        w2s[cc][k] = (k < 9) ? w2[cc * 9 + k] : 0.f;
    }
    if (t < kC * kCin) wsks[t] = wsk[t];
    if (t < kC) { b1s[t] = b1[t]; b2s[t] = b2[t]; bsks[t] = bsk[t]; }

    // stage x tile [bs-8, bs+40)
    for (int i = t; i < kCin * XB * FT; i += 256) {
        int fi = i % FT, xb = (i / FT) % XB, ci = i / (FT * XB);
        int gb = bs - 8 + xb;
        float v = 0.f;
        if (gb >= 0 && gb < kBins)
            v = x[((bb * kCin + ci) * kBins + gb) * kFrames + f0 + fi];
        xt[ci][xb][fi] = v;
    }
    __syncthreads();

    const int fi = t & 31;
    const int r = t >> 5; // 0..7

    // h1 stage
    for (int q = 0; q < 5; q++) {
        float a8[8];
        #pragma unroll
        for (int jj = 0; jj < 8; jj++) a8[jj] = b1s[r];
        #pragma unroll
        for (int ci = 0; ci < kCin; ci++) {
            float w[16];
            #pragma unroll
            for (int k = 0; k < 16; k++) w[k] = xt[ci][q * 8 + k][fi];
            const float* wp = &w1s[(r * kCin + ci) * 9];
            #pragma unroll
            for (int jj = 0; jj < 8; jj++)
                #pragma unroll
                for (int k = 0; k < 9; k++)
                    a8[jj] += w[jj + k] * wp[k];
        }
        #pragma unroll
        for (int jj = 0; jj < 8; jj++) {
            int hb = q * 8 + jj;
            int gb = bs - 4 + hb;
            float v = (gb >= 0 && gb < kBins) ? (a8[jj] > 0.f ? a8[jj] : 0.2f * a8[jj]) : 0.f;
            h1t[r][hb][fi] = v;
        }
    }
    __syncthreads();

    // main stage: thread (fi, r) computes v for 8 c x 4 bins (ob=r*4+j)
    float acc[8][4];
    #pragma unroll
    for (int c = 0; c < 8; c++)
        #pragma unroll
        for (int j = 0; j < 4; j++) acc[c][j] = b2s[c] + bsks[c];

    for (int ci = 0; ci < 8; ci++) {
        float w[12];
        #pragma unroll
        for (int k = 0; k < 12; k++) w[k] = h1t[ci][r * 4 + k][fi];
        #pragma unroll
        for (int c = 0; c < 8; c++) {
            const float4* wp4 = (const float4*)&w2s[c * 8 + ci][0];
            float4 wA = wp4[0], wB = wp4[1], wC = wp4[2];
            float wk[9] = {wA.x, wA.y, wA.z, wA.w, wB.x, wB.y, wB.z, wB.w, wC.x};
            #pragma unroll
            for (int j = 0; j < 4; j++) {
                float s = 0.f;
                #pragma unroll
                for (int k = 0; k < 9; k++) s += w[j + k] * wk[k];
                acc[c][j] += s;
            }
        }
    }
    // skip path
    #pragma unroll
    for (int j = 0; j < 4; j++) {
        float x0 = xt[0][r * 4 + j + 8][fi];
        float x1 = xt[1][r * 4 + j + 8][fi];
        #pragma unroll
        for (int c = 0; c < 8; c++)
            acc[c][j] += x0 * wsks[c * 2] + x1 * wsks[c * 2 + 1];
    }

    float sq = 0.f;
    #pragma unroll
    for (int c = 0; c < 8; c++)
        #pragma unroll
        for (int j = 0; j < 4; j++) sq += acc[c][j] * acc[c][j];

    // retile per channel: vbuf[ob][fi] -> write [n][k] f16 splits
    const int rr = t >> 3, q = t & 7;
    for (int c = 0; c < 8; c++) {
        __syncthreads();
        #pragma unroll
        for (int j = 0; j < 4; j++) vbuf[r * 4 + j][fi] = acc[c][j];
        __syncthreads();
        HPack4 ph, pl;
        #pragma unroll
        for (int j = 0; j < 4; j++) {
            float v = vbuf[q * 4 + j][rr];
            splitf(v, ph.h[j], pl.h[j]);
        }
        const int n = bb * kFrames + f0 + rr;
        const size_t off = ((size_t)(c * kN + n)) * kBins + bs + q * 4;
        *(uint2*)&V1[off] = ph.u;
        *(uint2*)&V2[off] = pl.u;
    }

    reds[t] = sq;
    __syncthreads();
    for (int off = 128; off > 0; off >>= 1) {
        if (t < off) reds[t] += reds[t + off];
        __syncthreads();
    }
    if (t == 0) {
        int blin = (bb * gridDim.y + blockIdx.y) * gridDim.x + blockIdx.x;
        partials[blin] = reds[0];
    }
}

// ================= codebook split + e2 (+ pk init) =================
__global__ __launch_bounds__(256) void cbsplit_e2(
    const float* __restrict__ cb, _Float16* __restrict__ B1,
    float* __restrict__ e2, unsigned long long* __restrict__ pk)
{
    const int gid = blockIdx.x * 256 + threadIdx.x;
    if (gid < kC * kN) pk[gid] = ~0ull;

    const int gw = gid >> 6;
    const int lane = threadIdx.x & 63;
    _Float16* B2 = B1 + (size_t)8388608;
    const float* row = cb + (size_t)gw * kBins;
    float s = 0.f;
    #pragma unroll
    for (int j = 0; j < 4; j++) {
        float4 v = *(const float4*)&row[lane * 4 + j * 256];
        s += v.x * v.x + v.y * v.y + v.z * v.z + v.w * v.w;
        HPack4 ph, pl;
        splitf(v.x, ph.h[0], pl.h[0]);
        splitf(v.y, ph.h[1], pl.h[1]);
        splitf(v.z, ph.h[2], pl.h[2]);
        splitf(v.w, ph.h[3], pl.h[3]);
        size_t off = (size_t)gw * kBins + lane * 4 + j * 256;
        *(uint2*)&B1[off] = ph.u;
        *(uint2*)&B2[off] = pl.u;
    }
    #pragma unroll
    for (int off = 32; off > 0; off >>= 1) s += __shfl_down(s, off);
    if (lane == 0) e2[gw] = s;
}

// ================= MFMA distance + argmin v2 ===============================
// 512-thread block (8 waves, 4wm x 2we), 256 n-rows x 512 E; 1 block/CU.
// 3 staging buffers x 48KB (A 32K + B 16K); counted vmcnt(6) pipeline:
// each wave issues 6 global_load_lds per k-step, 2 steps in flight, loads
// never drained inside the loop (vmcnt(0) only at the last step). K-order,
// swizzle, and accumulate order identical to r5 -> distances bit-identical.
__global__ __launch_bounds__(512, 2) void dist_mfma(
    const _Float16* __restrict__ V1, const _Float16* __restrict__ B1p,
    const float* __restrict__ e2, unsigned long long* __restrict__ pk)
{
    __shared__ char smem[3 * 49152 + 2048];

    const int t = threadIdx.x;
    const int bidx = blockIdx.x;
    const int ch = bidx & 7;
    const int eh = (bidx >> 3) & 1;
    const int n0 = (bidx >> 4) * 256;
    const int w = t >> 6, lane = t & 63;
    const int l15 = lane & 15, kc4 = lane >> 4;
    const int wm = w >> 1, we = w & 1;

    float* lds_e2 = (float*)(smem + 147456);
    lds_e2[t] = e2[ch * kE + eh * 512 + t];

    // staging source pointers (K-invariant parts); LDS dst = wave-uniform
    // base + lane*16 (required by global_load_lds), source per-lane swizzled
    const _Float16* srcA[4];
    int dstA[4];
    #pragma unroll
    for (int i = 0; i < 4; i++) {
        int ci = i * 512 + t;
        int row = ci >> 3, slot = ci & 7;
        int g = slot ^ (row & 7);
        int p = g >> 2, kc = g & 3;
        srcA[i] = V1 + (size_t)p * 33554432 + ((size_t)(ch * kN + n0 + row)) * kBins + kc * 8;
        dstA[i] = ci * 16;
    }
    const _Float16* srcB[2];
    int dstB[2];
    #pragma unroll
    for (int i = 0; i < 2; i++) {
        int bi = i * 512 + t;
        int row = bi >> 3, slot = bi & 7;
        int g = slot ^ (row & 7);
        int p = g >> 2, kc = g & 3;
        srcB[i] = B1p + (size_t)p * 8388608 + ((size_t)(ch * kE + row)) * kBins + kc * 8;
        dstB[i] = 32768 + bi * 16;
    }

    // fragment read bases (XOR-swizzled slots; conflict-free)
    const int rowA = wm * 64 + l15;           // + mi*16 below (rows 0..255)
    const int rowB = we * 64 + l15;           // e-rows 0..127
    const int baseA1 = rowA * 128 + ((kc4) ^ (rowA & 7)) * 16;
    const int baseA2 = rowA * 128 + ((4 + kc4) ^ (rowA & 7)) * 16;
    const int baseB1 = 32768 + rowB * 128 + ((kc4) ^ (rowB & 7)) * 16;
    const int baseB2 = 32768 + rowB * 128 + ((4 + kc4) ^ (rowB & 7)) * 16;

    float rm[16];
    int ri[16];
    #pragma unroll
    for (int s = 0; s < 16; s++) { rm[s] = 3.4e38f; ri[s] = 0; }

    typedef const __attribute__((address_space(1))) void gsrc_t;
    typedef __attribute__((address_space(3))) void gdst_t;

    auto issue = [&](int jj, int bw) {
        const int k0 = (jj & 31) * 32;
        const size_t etoff = (size_t)(eh * 4 + (jj >> 5)) * 128 * kBins + k0;
        char* nb = smem + bw * 49152;
        #pragma unroll
        for (int i = 0; i < 4; i++)
            __builtin_amdgcn_global_load_lds((gsrc_t*)(srcA[i] + k0), (gdst_t*)(nb + dstA[i]), 16, 0, 0);
        #pragma unroll
        for (int i = 0; i < 2; i++)
            __builtin_amdgcn_global_load_lds((gsrc_t*)(srcB[i] + etoff), (gdst_t*)(nb + dstB[i]), 16, 0, 0);
    };

    __syncthreads();            // e2 staged; LDS clean; vmcnt drained

    issue(0, 0);
    issue(1, 1);
    int bread = 0, bwrite = 2;

    #pragma unroll 1
    for (int et = 0; et < 4; et++) {
        f32x4 hi[4][4], lo[4][4];
        #pragma unroll
        for (int mi = 0; mi < 4; mi++)
            #pragma unroll
            for (int ei = 0; ei < 4; ei++) {
                hi[mi][ei] = (f32x4){0.f, 0.f, 0.f, 0.f};
                lo[mi][ei] = (f32x4){0.f, 0.f, 0.f, 0.f};
            }

        #pragma unroll 1
        for (int ks = 0; ks < 32; ks++) {
            const int j = et * 32 + ks;
            // retire the 6 loads of step j (2 newer steps stay in flight);
            // barrier also fences step j-1's reads of buffer (j+2)%3.
            if (j < 127)
                asm volatile("s_waitcnt vmcnt(6)\n\ts_barrier" ::: "memory");
            else
                asm volatile("s_waitcnt vmcnt(0)\n\ts_barrier" ::: "memory");
            if (j < 126) {
                issue(j + 2, bwrite);
                bwrite = (bwrite == 2) ? 0 : bwrite + 1;
            }

            const char* buf = smem + bread * 49152;
            bread = (bread == 2) ? 0 : bread + 1;

            f16x8 a1[4], a2[4], b1f[4], b2f[4];
            #pragma unroll
            for (int mi = 0; mi < 4; mi++) {
                a1[mi] = *(const f16x8*)(buf + baseA1 + mi * 2048);
                a2[mi] = *(const f16x8*)(buf + baseA2 + mi * 2048);
            }
            #pragma unroll
            for (int ei = 0; ei < 4; ei++) {
                b1f[ei] = *(const f16x8*)(buf + baseB1 + ei * 2048);
                b2f[ei] = *(const f16x8*)(buf + baseB2 + ei * 2048);
            }
            __builtin_amdgcn_s_setprio(1);
            #pragma unroll
            for (int mi = 0; mi < 4; mi++)
                #pragma unroll
                for (int ei = 0; ei < 4; ei++) {
                    hi[mi][ei] = __builtin_amdgcn_mfma_f32_16x16x32_f16(a1[mi], b1f[ei], hi[mi][ei], 0, 0, 0);
                    lo[mi][ei] = __builtin_amdgcn_mfma_f32_16x16x32_f16(a1[mi], b2f[ei], lo[mi][ei], 0, 0, 0);
                    lo[mi][ei] = __builtin_amdgcn_mfma_f32_16x16x32_f16(a2[mi], b1f[ei], lo[mi][ei], 0, 0, 0);
                }
            __builtin_amdgcn_s_setprio(0);
        }

        // epilogue: running argmin (ascending e, strict <); e2 from LDS
        #pragma unroll
        for (int ei = 0; ei < 4; ei++) {
            const int eloc = et * 128 + we * 64 + ei * 16 + l15;
            const float ev = lds_e2[eloc];
            const int eix = eh * 512 + eloc;
            #pragma unroll
            for (int mi = 0; mi < 4; mi++) {
                f32x4 dot4 = hi[mi][ei] + lo[mi][ei] * (1.0f / 4096.0f);
                #pragma unroll
                for (int rr = 0; rr < 4; rr++) {
                    float d = ev - 2.0f * dot4[rr];
                    int s = mi * 4 + rr;
                    if (d < rm[s]) { rm[s] = d; ri[s] = eix; }
                }
            }
        }
    }

    // cross-lane reduce over the 16 lanes (l15) sharing the same rows
    #pragma unroll
    for (int m = 1; m < 16; m <<= 1) {
        #pragma unroll
        for (int s = 0; s < 16; s++) {
            float ov = __shfl_xor(rm[s], m);
            int oi = __shfl_xor(ri[s], m);
            if (ov < rm[s] || (ov == rm[s] && oi < ri[s])) { rm[s] = ov; ri[s] = oi; }
        }
    }

    // merge the 2 we-waves sharing each row range (smem reuse after barrier)
    float* mv = (float*)smem;           // [256][2]
    int* miv = (int*)(smem + 2048);     // [256][2]
    __syncthreads();
    if (l15 == 0) {
        #pragma unroll
        for (int s = 0; s < 16; s++) {
            int mi = s >> 2, rr = s & 3;
            int rloc = wm * 64 + mi * 16 + (lane >> 4) * 4 + rr;
            mv[rloc * 2 + we] = rm[s];
            miv[rloc * 2 + we] = ri[s];
        }
    }
    __syncthreads();
    if (t < 256) {
        float v0 = mv[t * 2], v1 = mv[t * 2 + 1];
        int i0 = miv[t * 2], i1 = miv[t * 2 + 1];
        bool take1 = (v1 < v0) || (v1 == v0 && i1 < i0);
        float bv = take1 ? v1 : v0;
        int bi = take1 ? i1 : i0;
        // packed deterministic cross-block min-merge: sortable f32 | idx
        unsigned int u = __float_as_uint(bv);
        unsigned int su = (u & 0x80000000u) ? ~u : (u ^ 0x80000000u);
        unsigned long long packed = ((unsigned long long)su << 32) | (unsigned int)bi;
        atomicMin(&pk[ch * kN + n0 + t], packed);
    }
}

// ================= gather (cp-XCD affine) + fused loss =====================
__global__ __launch_bounds__(256) void gather_pk(
    const float* __restrict__ cb, const unsigned long long* __restrict__ pk,
    const float* __restrict__ partials, float* __restrict__ out,
    float* __restrict__ loss)
{
    const int t = threadIdx.x;
    const int lane = t & 63, q = t >> 6;
    const int b = blockIdx.x;
    const int cp = b & 7;            // channel -> XCD affinity
    const int bt = (b >> 3) & 63;
    const int ftile = (b >> 9) & 7;
    const int bb = b >> 12;
    const int co = (kC - 1) - cp;
    const int f = ftile * 64 + lane;
    const int n = bb * kFrames + f;
    const int e = (int)(unsigned int)(pk[cp * kN + n] & 0xFFFFFFFFull);
    const int bin0 = bt * 16 + q * 4;
    const float4 v4 = *(const float4*)&cb[((size_t)cp * kE + e) * kBins + bin0];
    const size_t base = ((size_t)(bb * kC + co) * kBins + bin0) * kFrames + f;
    out[base] = v4.x;
    out[base + kFrames] = v4.y;
    out[base + 2 * (size_t)kFrames] = v4.z;
    out[base + 3 * (size_t)kFrames] = v4.w;

    if (b == 32767) {
        __shared__ float reds[256];
        float s = 0.f;
        for (int i = t; i < kC * kN; i += 256) {
            unsigned int su = (unsigned int)(pk[i] >> 32);
            unsigned int u = (su & 0x80000000u) ? (su ^ 0x80000000u) : ~su;
            s += __uint_as_float(u);
        }
        for (int i = t; i < 4096; i += 256) s += partials[i];
        reds[t] = s;
        __syncthreads();
        for (int off = 128; off > 0; off >>= 1) {
            if (t < off) reds[t] += reds[t + off];
            __syncthreads();
        }
        if (t == 0) loss[0] = 1.25f * reds[0] / (float)(kN * kBins);
    }
}

} // namespace

extern "C" void kernel_launch(void* const* d_in, const int* in_sizes, int n_in,
                              void* d_out, int out_size, void* d_ws, size_t ws_size,
                              hipStream_t stream)
{
    const float* x   = (const float*)d_in[0];
    const float* w1  = (const float*)d_in[1];
    const float* b1  = (const float*)d_in[2];
    const float* w2  = (const float*)d_in[3];
    const float* b2  = (const float*)d_in[4];
    const float* wsk = (const float*)d_in[5];
    const float* bsk = (const float*)d_in[6];
    const float* cb  = (const float*)d_in[7];
    float* out = (float*)d_out;
    char* ws = (char*)d_ws;

    // ws layout: B1|B2 32M | e2 32K | pk 256K | partials 16K
    _Float16* B1 = (_Float16*)ws;
    float* e2                  = (float*)(ws + 33554432);
    unsigned long long* pk     = (unsigned long long*)(ws + 33554432 + 32768);
    float* partials            = (float*)(ws + 33554432 + 32768 + 262144);
    _Float16* V1 = (_Float16*)d_out; // V1 67MB | V2 67MB, overwritten by gather

    conv_fused_v2<<<dim3(kBins / BT, kFrames / FT, kB), 256, 0, stream>>>(
        x, w1, b1, w2, b2, wsk, bsk, V1, partials);
    cbsplit_e2<<<(kC * kE) / 4, 256, 0, stream>>>(cb, B1, e2, pk);
    dist_mfma<<<dim3(256), 512, 0, stream>>>(V1, B1, e2, pk);
    gather_pk<<<dim3(32768), 256, 0, stream>>>(cb, pk, partials, out,
                                               out + (size_t)kC * kBins * kN);
}